// Round 13
// baseline (127.169 us; speedup 1.0000x reference)
//
#include <hip/hip_runtime.h>
#include <hip/hip_bf16.h>

// Problem constants (P=1 folded out everywhere)
#define NB   8      // batch
#define NA   8      // actions
#define ND   8      // dim_qk
#define NCH  64     // NA*ND q/k channels
#define GT   32     // grid T=H=W
#define KREG 216    // 6^3 halo voxels
#define IMS  40     // im2col/weight row stride in halfwords (80 B)

// LDS pool overlays (bytes):
//  build window: xS[0,2048) BTS[2048,13568) imc[13568,31488)
//  attn  window: kvS[0,31104) qS[31104,40320)  (xS/BTS/imc dead by then)
#define XS_OFF   0
#define BTS_OFF  2048
#define IMC_OFF  13568
#define KV_OFF   0
#define QS_OFF   31104
#define POOL_SZ  40320    // <= 40960 -> 4 blocks/CU

typedef _Float16 h2_t  __attribute__((ext_vector_type(2)));
typedef _Float16 f16x8 __attribute__((ext_vector_type(8)));
typedef float    f32x4 __attribute__((ext_vector_type(4)));

static __device__ __forceinline__ unsigned pack_h2(float a, float b) {
#if __has_builtin(__builtin_amdgcn_cvt_pkrtz)
    return __builtin_bit_cast(unsigned, __builtin_amdgcn_cvt_pkrtz(a, b));
#else
    unsigned short ha = __builtin_bit_cast(unsigned short, (_Float16)a);
    unsigned short hb = __builtin_bit_cast(unsigned short, (_Float16)b);
    return (unsigned)ha | ((unsigned)hb << 16);
#endif
}

static __device__ __forceinline__ float dot2(unsigned k, unsigned q, float c) {
#if __has_builtin(__builtin_amdgcn_fdot2)
    return __builtin_amdgcn_fdot2(__builtin_bit_cast(h2_t, k),
                                  __builtin_bit_cast(h2_t, q), c, false);
#else
    h2_t a = __builtin_bit_cast(h2_t, k), b = __builtin_bit_cast(h2_t, q);
    return c + (float)a[0] * (float)b[0] + (float)a[1] * (float)b[1];
#endif
}

// Single-dispatch kernel (round-12 verified structure, prep folded in).
// Weight image [144][IMS] fp16 built per block: rows 0..63 k (w_qk 64..127),
// 64..71 softmax(w_v), 72..79 zero, 80..143 q (w_qk 0..63 scaled by log2e).
// One unified MFMA pass (shared B-frags) -> kvS + qS; merged two-action
// phase C (no xr[] live anymore -> fits without the round-9 spill).
__launch_bounds__(256, 4)
__global__ void avi_kernel(const float* __restrict__ values,
                           const float* __restrict__ rewards,
                           const float* __restrict__ w_qk,
                           const float* __restrict__ w_v,
                           float* __restrict__ out) {
    __shared__ __align__(16) char pool[POOL_SZ];
    float*    xS   = (float*)(pool + XS_OFF);
    _Float16* BTSl = (_Float16*)(pool + BTS_OFF);
    _Float16* imc  = (_Float16*)(pool + IMC_OFF);
    char*     kvS  = pool + KV_OFF;      // [216][144B]: units 0..7 k, unit 8 v
    char*     qS   = pool + QS_OFF;      // [64][144B]: 8 a x 16B q + 16B hole

    const int tid  = threadIdx.x;
    const int bb   = blockIdx.x >> 9;      // batch
    const int tile = blockIdx.x & 511;     // 8x8x8 tiles of 4^3
    const int tz = tile >> 6, ty = (tile >> 3) & 7, tx = tile & 7;
    const int g0z = tz * 4, g0y = ty * 4, g0x = tx * 4;
    const int base_in = bb * (GT * GT * GT);

    // ---- Phase A: x staging + in-block weight-image build ----
    for (int i = tid; i < 512; i += 256) {
        int lz = i >> 6, ly = (i >> 3) & 7, lx = i & 7;
        int gz = g0z + lz - 2, gy = g0y + ly - 2, gx = g0x + lx - 2;
        float v = 0.f;
        if ((unsigned)gz < 32u && (unsigned)gy < 32u && (unsigned)gx < 32u) {
            int idx = base_in + gz * 1024 + gy * 32 + gx;
            v = values[idx] + rewards[idx];
        }
        xS[i] = v;
    }
    if (tid < 144) {
        float r[28];
        r[27] = 0.f;
        if (tid < 64) {
            const float* w = w_qk + (NCH + tid) * 27;
            #pragma unroll
            for (int j = 0; j < 27; ++j) r[j] = w[j];
        } else if (tid < 72) {
            int a = tid - 64;
            float m = -1e30f;
            #pragma unroll
            for (int j = 0; j < 27; ++j) { r[j] = w_v[a * 27 + j]; m = fmaxf(m, r[j]); }
            float s = 0.f;
            #pragma unroll
            for (int j = 0; j < 27; ++j) { r[j] = __expf(r[j] - m); s += r[j]; }
            float inv = 1.f / s;
            #pragma unroll
            for (int j = 0; j < 27; ++j) r[j] *= inv;
        } else if (tid < 80) {
            #pragma unroll
            for (int j = 0; j < 27; ++j) r[j] = 0.f;
        } else {
            const float* w = w_qk + (tid - 80) * 27;
            const float L2E = 1.44269504f;
            #pragma unroll
            for (int j = 0; j < 27; ++j) r[j] = w[j] * L2E;
        }
        unsigned* dst = (unsigned*)(BTSl + tid * IMS);
        #pragma unroll
        for (int p = 0; p < 14; ++p) dst[p] = pack_h2(r[2 * p], r[2 * p + 1]);
        #pragma unroll
        for (int p = 14; p < 20; ++p) dst[p] = 0u;
    }
    __syncthreads();

    // ---- Phase B1: im2col fp16 [224][IMS] (OOB voxel columns zeroed) ----
    if (tid < 224) {
        unsigned rowU[16];
        if (tid < KREG) {
            int vz = tid / 36, rem = tid - vz * 36, vy = rem / 6, vx = rem - vy * 6;
            int gz = g0z + vz - 1, gy = g0y + vy - 1, gx = g0x + vx - 1;
            float mask = ((unsigned)gz < 32u && (unsigned)gy < 32u && (unsigned)gx < 32u)
                             ? 1.f : 0.f;
            float xr[27];
            #pragma unroll
            for (int t = 0; t < 27; ++t) {
                int dz = t / 9, dy = (t / 3) % 3, dx = t % 3;
                xr[t] = xS[(vz + dz) * 64 + (vy + dy) * 8 + (vx + dx)] * mask;
            }
            #pragma unroll
            for (int p = 0; p < 13; ++p) rowU[p] = pack_h2(xr[2 * p], xr[2 * p + 1]);
            rowU[13] = pack_h2(xr[26], 0.f);
            rowU[14] = rowU[15] = 0u;
        } else {
            #pragma unroll
            for (int p = 0; p < 16; ++p) rowU[p] = 0u;
        }
        int4* dst = (int4*)((char*)imc + tid * (IMS * 2));
        dst[0] = make_int4(rowU[0], rowU[1], rowU[2], rowU[3]);
        dst[1] = make_int4(rowU[4], rowU[5], rowU[6], rowU[7]);
        dst[2] = make_int4(rowU[8], rowU[9], rowU[10], rowU[11]);
        dst[3] = make_int4(rowU[12], rowU[13], rowU[14], rowU[15]);
    }

    const int lane = tid & 63;
    const int wave = tid >> 6;
    const int quad = lane >> 4;
    const int l15  = lane & 15;

    // A-frags: A[m=l15][k=quad*8+j]; stride 40 halfs -> 2-way (free)
    f16x8 af[9];
    #pragma unroll
    for (int mt = 0; mt < 9; ++mt)
        af[mt] = *(const f16x8*)(BTSl + (mt * 16 + l15) * IMS + quad * 8);

    __syncthreads();   // im2col ready

    f16x8 bf[4];
    #pragma unroll
    for (int i = 0; i < 4; ++i) {
        int nt = wave + i * 4;
        if (nt < 14)
            bf[i] = *(const f16x8*)(imc + (nt * 16 + l15) * IMS + quad * 8);
    }

    __syncthreads();   // frag loads done -> build window reusable as kvS/qS

    // ---- Phase B2: unified MFMA; k,v -> kvS rows, q -> qS rows ----
    for (int i = 0; i < 4; ++i) {
        int nt = wave + i * 4;
        if (nt >= 14) break;
        int n = nt * 16 + l15;
        bool nvalid = (n < KREG);
        int vz = n / 36, rm = n - vz * 36, vy = rm / 6, vx = rm - vy * 6;
        bool ctr = ((unsigned)(vz - 1) < 4u) && ((unsigned)(vy - 1) < 4u) &&
                   ((unsigned)(vx - 1) < 4u);
        int cvox = (vz - 1) * 16 + (vy - 1) * 4 + (vx - 1);
        char* rowB = kvS + n * 144;
        char* rowQ = qS + cvox * 144;
        #pragma unroll
        for (int mt = 0; mt < 9; ++mt) {
            f32x4 d = __builtin_amdgcn_mfma_f32_16x16x32_f16(
                af[mt], bf[i], (f32x4){0.f, 0.f, 0.f, 0.f}, 0, 0, 0);
            if (mt < 4) {                       // k ch = mt*16 + quad*4 + reg
                if (nvalid) {
                    int2 w2;
                    w2.x = (int)pack_h2(d[0], d[1]);
                    w2.y = (int)pack_h2(d[2], d[3]);
                    *(int2*)(rowB + (mt * 16 + quad * 4) * 2) = w2;
                }
            } else if (mt == 4) {               // v actions quad*4+reg (quad<2)
                if (nvalid && quad < 2) {
                    int2 w2;
                    w2.x = (int)pack_h2(d[0], d[1]);
                    w2.y = (int)pack_h2(d[2], d[3]);
                    *(int2*)(rowB + 128 + quad * 8) = w2;
                }
            } else {                            // q ch = (mt-5)*16 + quad*4
                if (ctr) {
                    int ch0 = (mt - 5) * 16 + quad * 4;
                    int a = ch0 >> 3, d0 = ch0 & 7;
                    int2 w2;
                    w2.x = (int)pack_h2(d[0], d[1]);
                    w2.y = (int)pack_h2(d[2], d[3]);
                    *(int2*)(rowQ + a * 16 + d0 * 2) = w2;
                }
            }
        }
    }
    __syncthreads();

    // ---- Phase C: merged two-action attention (shared addr + v reads) ----
    const int clz = lane >> 4, cly = (lane >> 2) & 3, clx = lane & 3;
    const int rbase = clz * 36 + cly * 6 + clx;
    const int a0 = wave, a1 = wave + 4;
    const unsigned vsh = (wave & 1) * 16;

    const int4 qv0 = *(const int4*)(qS + lane * 144 + a0 * 16);
    const int4 qv1 = *(const int4*)(qS + lane * 144 + a1 * 16);
    unsigned qp0[4] = {(unsigned)qv0.x, (unsigned)qv0.y,
                       (unsigned)qv0.z, (unsigned)qv0.w};
    unsigned qp1[4] = {(unsigned)qv1.x, (unsigned)qv1.y,
                       (unsigned)qv1.z, (unsigned)qv1.w};

    float ssum0 = 0.f, acc0 = 0.f, ssum1 = 0.f, acc1 = 0.f;
    #pragma unroll
    for (int nn = 0; nn < 27; ++nn) {
        int dz = nn / 9, dy = (nn / 3) % 3, dx = nn % 3;
        int r = rbase + dz * 36 + dy * 6 + dx;
        const char* rowB = kvS + r * 144;
        const int4 k0 = *(const int4*)(rowB + a0 * 16);
        const int4 k1 = *(const int4*)(rowB + a1 * 16);
        const int4 vu = *(const int4*)(rowB + 128);
        float s0 = dot2((unsigned)k0.x, qp0[0],
                   dot2((unsigned)k0.y, qp0[1],
                   dot2((unsigned)k0.z, qp0[2],
                   dot2((unsigned)k0.w, qp0[3], 0.f))));
        float s1 = dot2((unsigned)k1.x, qp1[0],
                   dot2((unsigned)k1.y, qp1[1],
                   dot2((unsigned)k1.z, qp1[2],
                   dot2((unsigned)k1.w, qp1[3], 0.f))));
        float e0 = exp2f(s0);
        float e1 = exp2f(s1);
        unsigned hw0 = ((const unsigned*)&vu)[wave >> 1];
        unsigned hw1 = ((const unsigned*)&vu)[(wave >> 1) + 2];
        float v0 = (float)__builtin_bit_cast(_Float16,
                       (unsigned short)((hw0 >> vsh) & 0xffffu));
        float v1 = (float)__builtin_bit_cast(_Float16,
                       (unsigned short)((hw1 >> vsh) & 0xffffu));
        ssum0 += e0; acc0 = fmaf(e0, v0, acc0);
        ssum1 += e1; acc1 = fmaf(e1, v1, acc1);
    }
    float best = fmaxf(acc0 / ssum0, acc1 / ssum1);
    // result partials live in qS row holes (bytes 128..143)
    *(float*)(qS + lane * 144 + 128 + wave * 4) = best;
    __syncthreads();

    // ---- max over actions (4 wave-partials) -> fp32 output ----
    if (tid < 64) {
        float4 p = *(const float4*)(qS + tid * 144 + 128);
        float mx = fmaxf(fmaxf(p.x, p.y), fmaxf(p.z, p.w));
        int lz2 = tid >> 4, ly2 = (tid >> 2) & 3, lx2 = tid & 3;
        int o = base_in + (g0z + lz2) * 1024 + (g0y + ly2) * 32 + (g0x + lx2);
        out[o] = mx;
    }
}

extern "C" void kernel_launch(void* const* d_in, const int* in_sizes, int n_in,
                              void* d_out, int out_size, void* d_ws, size_t ws_size,
                              hipStream_t stream) {
    const float* values  = (const float*)d_in[0];
    const float* rewards = (const float*)d_in[1];
    const float* w_qk    = (const float*)d_in[2];
    const float* w_v     = (const float*)d_in[3];
    avi_kernel<<<NB * 512, 256, 0, stream>>>(values, rewards, w_qk, w_v,
                                             (float*)d_out);
}

// Round 14
// 106.768 us; speedup vs baseline: 1.1911x; 1.1911x over previous
//
#include <hip/hip_runtime.h>
#include <hip/hip_bf16.h>

// Problem constants (P=1 folded out everywhere)
#define NB   8      // batch
#define NA   8      // actions
#define ND   8      // dim_qk
#define NCH  64     // NA*ND q/k channels
#define GT   32     // grid T=H=W
#define KREG 216    // 6^3 halo voxels
#define IMS  40     // im2col/weight row stride in halfwords (80 B)

// LDS pool overlays (bytes):
//  build window: xS[0,2048) BTS[2048,13568) imc[13568,31488)
//  attn  window: kvS[0,31104) qS[31104,40320)  (xS/BTS/imc dead by then)
#define XS_OFF   0
#define BTS_OFF  2048
#define IMC_OFF  13568
#define KV_OFF   0
#define QS_OFF   31104
#define POOL_SZ  40320    // <= 40960 -> 4 blocks/CU

typedef _Float16 h2_t  __attribute__((ext_vector_type(2)));
typedef _Float16 f16x8 __attribute__((ext_vector_type(8)));
typedef float    f32x4 __attribute__((ext_vector_type(4)));

static __device__ __forceinline__ unsigned pack_h2(float a, float b) {
#if __has_builtin(__builtin_amdgcn_cvt_pkrtz)
    return __builtin_bit_cast(unsigned, __builtin_amdgcn_cvt_pkrtz(a, b));
#else
    unsigned short ha = __builtin_bit_cast(unsigned short, (_Float16)a);
    unsigned short hb = __builtin_bit_cast(unsigned short, (_Float16)b);
    return (unsigned)ha | ((unsigned)hb << 16);
#endif
}

static __device__ __forceinline__ float dot2(unsigned k, unsigned q, float c) {
#if __has_builtin(__builtin_amdgcn_fdot2)
    return __builtin_amdgcn_fdot2(__builtin_bit_cast(h2_t, k),
                                  __builtin_bit_cast(h2_t, q), c, false);
#else
    h2_t a = __builtin_bit_cast(h2_t, k), b = __builtin_bit_cast(h2_t, q);
    return c + (float)a[0] * (float)b[0] + (float)a[1] * (float)b[1];
#endif
}

// Single-dispatch kernel: round-13 phase A (in-block weight build, verified
// cheap) + round-12 per-action phase C (verified 54 us kernel).
// THREE-TIMES-CONFIRMED RULE (r9/r13): phase C must keep ONE action's state
// live; merging both actions spills 1 VGPR -> WRITE_SIZE 2->6 MB, +26-35 us.
__launch_bounds__(256, 4)
__global__ void avi_kernel(const float* __restrict__ values,
                           const float* __restrict__ rewards,
                           const float* __restrict__ w_qk,
                           const float* __restrict__ w_v,
                           float* __restrict__ out) {
    __shared__ __align__(16) char pool[POOL_SZ];
    float*    xS   = (float*)(pool + XS_OFF);
    _Float16* BTSl = (_Float16*)(pool + BTS_OFF);
    _Float16* imc  = (_Float16*)(pool + IMC_OFF);
    char*     kvS  = pool + KV_OFF;      // [216][144B]: units 0..7 k, unit 8 v
    char*     qS   = pool + QS_OFF;      // [64][144B]: 8 a x 16B q + 16B hole

    const int tid  = threadIdx.x;
    const int bb   = blockIdx.x >> 9;      // batch
    const int tile = blockIdx.x & 511;     // 8x8x8 tiles of 4^3
    const int tz = tile >> 6, ty = (tile >> 3) & 7, tx = tile & 7;
    const int g0z = tz * 4, g0y = ty * 4, g0x = tx * 4;
    const int base_in = bb * (GT * GT * GT);

    // ---- Phase A: x staging + in-block weight-image build ----
    for (int i = tid; i < 512; i += 256) {
        int lz = i >> 6, ly = (i >> 3) & 7, lx = i & 7;
        int gz = g0z + lz - 2, gy = g0y + ly - 2, gx = g0x + lx - 2;
        float v = 0.f;
        if ((unsigned)gz < 32u && (unsigned)gy < 32u && (unsigned)gx < 32u) {
            int idx = base_in + gz * 1024 + gy * 32 + gx;
            v = values[idx] + rewards[idx];
        }
        xS[i] = v;
    }
    if (tid < 144) {
        float r[28];
        r[27] = 0.f;
        if (tid < 64) {
            const float* w = w_qk + (NCH + tid) * 27;
            #pragma unroll
            for (int j = 0; j < 27; ++j) r[j] = w[j];
        } else if (tid < 72) {
            int a = tid - 64;
            float m = -1e30f;
            #pragma unroll
            for (int j = 0; j < 27; ++j) { r[j] = w_v[a * 27 + j]; m = fmaxf(m, r[j]); }
            float s = 0.f;
            #pragma unroll
            for (int j = 0; j < 27; ++j) { r[j] = __expf(r[j] - m); s += r[j]; }
            float inv = 1.f / s;
            #pragma unroll
            for (int j = 0; j < 27; ++j) r[j] *= inv;
        } else if (tid < 80) {
            #pragma unroll
            for (int j = 0; j < 27; ++j) r[j] = 0.f;
        } else {
            const float* w = w_qk + (tid - 80) * 27;
            const float L2E = 1.44269504f;
            #pragma unroll
            for (int j = 0; j < 27; ++j) r[j] = w[j] * L2E;
        }
        unsigned* dst = (unsigned*)(BTSl + tid * IMS);
        #pragma unroll
        for (int p = 0; p < 14; ++p) dst[p] = pack_h2(r[2 * p], r[2 * p + 1]);
        #pragma unroll
        for (int p = 14; p < 20; ++p) dst[p] = 0u;
    }
    __syncthreads();

    // ---- Phase B1: im2col fp16 [224][IMS] (OOB voxel columns zeroed) ----
    if (tid < 224) {
        unsigned rowU[16];
        if (tid < KREG) {
            int vz = tid / 36, rem = tid - vz * 36, vy = rem / 6, vx = rem - vy * 6;
            int gz = g0z + vz - 1, gy = g0y + vy - 1, gx = g0x + vx - 1;
            float mask = ((unsigned)gz < 32u && (unsigned)gy < 32u && (unsigned)gx < 32u)
                             ? 1.f : 0.f;
            float xr[27];
            #pragma unroll
            for (int t = 0; t < 27; ++t) {
                int dz = t / 9, dy = (t / 3) % 3, dx = t % 3;
                xr[t] = xS[(vz + dz) * 64 + (vy + dy) * 8 + (vx + dx)] * mask;
            }
            #pragma unroll
            for (int p = 0; p < 13; ++p) rowU[p] = pack_h2(xr[2 * p], xr[2 * p + 1]);
            rowU[13] = pack_h2(xr[26], 0.f);
            rowU[14] = rowU[15] = 0u;
        } else {
            #pragma unroll
            for (int p = 0; p < 16; ++p) rowU[p] = 0u;
        }
        int4* dst = (int4*)((char*)imc + tid * (IMS * 2));
        dst[0] = make_int4(rowU[0], rowU[1], rowU[2], rowU[3]);
        dst[1] = make_int4(rowU[4], rowU[5], rowU[6], rowU[7]);
        dst[2] = make_int4(rowU[8], rowU[9], rowU[10], rowU[11]);
        dst[3] = make_int4(rowU[12], rowU[13], rowU[14], rowU[15]);
    }

    const int lane = tid & 63;
    const int wave = tid >> 6;
    const int quad = lane >> 4;
    const int l15  = lane & 15;

    // A-frags: A[m=l15][k=quad*8+j]; stride 40 halfs -> 2-way (free)
    f16x8 af[9];
    #pragma unroll
    for (int mt = 0; mt < 9; ++mt)
        af[mt] = *(const f16x8*)(BTSl + (mt * 16 + l15) * IMS + quad * 8);

    __syncthreads();   // im2col ready

    f16x8 bf[4];
    #pragma unroll
    for (int i = 0; i < 4; ++i) {
        int nt = wave + i * 4;
        if (nt < 14)
            bf[i] = *(const f16x8*)(imc + (nt * 16 + l15) * IMS + quad * 8);
    }

    __syncthreads();   // frag loads done -> build window reusable as kvS/qS

    // ---- Phase B2: unified MFMA; k,v -> kvS rows, q -> qS rows ----
    for (int i = 0; i < 4; ++i) {
        int nt = wave + i * 4;
        if (nt >= 14) break;
        int n = nt * 16 + l15;
        bool nvalid = (n < KREG);
        int vz = n / 36, rm = n - vz * 36, vy = rm / 6, vx = rm - vy * 6;
        bool ctr = ((unsigned)(vz - 1) < 4u) && ((unsigned)(vy - 1) < 4u) &&
                   ((unsigned)(vx - 1) < 4u);
        int cvox = (vz - 1) * 16 + (vy - 1) * 4 + (vx - 1);
        char* rowB = kvS + n * 144;
        char* rowQ = qS + cvox * 144;
        #pragma unroll
        for (int mt = 0; mt < 9; ++mt) {
            f32x4 d = __builtin_amdgcn_mfma_f32_16x16x32_f16(
                af[mt], bf[i], (f32x4){0.f, 0.f, 0.f, 0.f}, 0, 0, 0);
            if (mt < 4) {                       // k ch = mt*16 + quad*4 + reg
                if (nvalid) {
                    int2 w2;
                    w2.x = (int)pack_h2(d[0], d[1]);
                    w2.y = (int)pack_h2(d[2], d[3]);
                    *(int2*)(rowB + (mt * 16 + quad * 4) * 2) = w2;
                }
            } else if (mt == 4) {               // v actions quad*4+reg (quad<2)
                if (nvalid && quad < 2) {
                    int2 w2;
                    w2.x = (int)pack_h2(d[0], d[1]);
                    w2.y = (int)pack_h2(d[2], d[3]);
                    *(int2*)(rowB + 128 + quad * 8) = w2;
                }
            } else {                            // q ch = (mt-5)*16 + quad*4
                if (ctr) {
                    int ch0 = (mt - 5) * 16 + quad * 4;
                    int a = ch0 >> 3, d0 = ch0 & 7;
                    int2 w2;
                    w2.x = (int)pack_h2(d[0], d[1]);
                    w2.y = (int)pack_h2(d[2], d[3]);
                    *(int2*)(rowQ + a * 16 + d0 * 2) = w2;
                }
            }
        }
    }
    __syncthreads();

    // ---- Phase C: PER-ACTION attention (round-12 verified; one action's
    // state live at a time — do not merge, see rule above) ----
    const int clz = lane >> 4, cly = (lane >> 2) & 3, clx = lane & 3;
    const int rbase = clz * 36 + cly * 6 + clx;

    float best = -1e30f;
    #pragma unroll
    for (int ti = 0; ti < 2; ++ti) {
        int a = wave + ti * 4;                    // wave-uniform
        const int4 qv = *(const int4*)(qS + lane * 144 + a * 16);
        unsigned qp[4] = {(unsigned)qv.x, (unsigned)qv.y,
                          (unsigned)qv.z, (unsigned)qv.w};
        float ssum = 0.f, acc = 0.f;
        #pragma unroll
        for (int nn = 0; nn < 27; ++nn) {
            int dz = nn / 9, dy = (nn / 3) % 3, dx = nn % 3;
            int r = rbase + dz * 36 + dy * 6 + dx;
            const char* rowB = kvS + r * 144;
            const int4 kr = *(const int4*)(rowB + a * 16);
            float s = dot2((unsigned)kr.x, qp[0],
                      dot2((unsigned)kr.y, qp[1],
                      dot2((unsigned)kr.z, qp[2],
                      dot2((unsigned)kr.w, qp[3], 0.f))));
            float e = exp2f(s);
            float fv = (float)*(const _Float16*)(rowB + 128 + a * 2);
            ssum += e;
            acc = fmaf(e, fv, acc);
        }
        best = fmaxf(best, acc / ssum);
    }
    // result partials live in qS row holes (bytes 128..143)
    *(float*)(qS + lane * 144 + 128 + wave * 4) = best;
    __syncthreads();

    // ---- max over actions (4 wave-partials) -> fp32 output ----
    if (tid < 64) {
        float4 p = *(const float4*)(qS + tid * 144 + 128);
        float mx = fmaxf(fmaxf(p.x, p.y), fmaxf(p.z, p.w));
        int lz2 = tid >> 4, ly2 = (tid >> 2) & 3, lx2 = tid & 3;
        int o = base_in + (g0z + lz2) * 1024 + (g0y + ly2) * 32 + (g0x + lx2);
        out[o] = mx;
    }
}

extern "C" void kernel_launch(void* const* d_in, const int* in_sizes, int n_in,
                              void* d_out, int out_size, void* d_ws, size_t ws_size,
                              hipStream_t stream) {
    const float* values  = (const float*)d_in[0];
    const float* rewards = (const float*)d_in[1];
    const float* w_qk    = (const float*)d_in[2];
    const float* w_v     = (const float*)d_in[3];
    avi_kernel<<<NB * 512, 256, 0, stream>>>(values, rewards, w_qk, w_v,
                                             (float*)d_out);
}